// Round 12
// baseline (329.025 us; speedup 1.0000x reference)
//
#include <hip/hip_runtime.h>

// ---------------------------------------------------------------------------
// VanillaSFNN split pipeline (r7 structure) + W-in-VGPR gemm.
//   k0 wprep  : W_h -> split bf16 hi/lo, BK=32 fragment tiles (22 x 8KB)
//   k1 gemm   : 2000 blocks x 256 thr (4 waves). Wave = n-frag, owns its W
//               fragments in VGPRs (22 x hi/lo = 176 regs); computes all 8
//               m-frags (8 independent acc chains). x staged via
//               global_load_lds ring-2 (16KB tiles), pure-x counted vmcnt(4).
//               32KB LDS -> 4 blocks/CU. cur in t-quad layout [r/4][h][4].
//   k2 lif    : chunked speculative scan (burn-in 40), coalesced f32x4 loads
//   k3 readout: per-batch fused scan, 512 thr (r7's proven 12us)
// ---------------------------------------------------------------------------

typedef float  f32x4  __attribute__((ext_vector_type(4)));
typedef short  short8 __attribute__((ext_vector_type(8)));
typedef unsigned long long ull;

#define B_   256
#define T_   1000
#define K_   700
#define H_   64
#define O_   20
#define NKT  22          // k-tiles of BK=32 (704 padded)
#define NCH  200         // readout chunks
#define TCH  5
#define TCL  100         // LIF chunk length
#define NCL  10          // LIF chunks
#define BIL  40          // LIF burn-in steps

// workspace layout (bytes)
#define OFF_WFRAG  ((size_t)0)            // 22*8192 = 180,224
#define OFF_CUR    ((size_t)262144)       // 256000*64*4 = 65,536,000
#define OFF_MASK   ((size_t)65798144)     // 256000*8    =  2,048,000

// ---------------------------------------------------------------------------
// k0: W_h -> split-bf16 fragments, BK=32 tiles. Tile kt = 4096 shorts (8KB):
// hi 256 chunks x 8, lo at +2048 shorts. slot = nf*64+lane:
// h = nf*16+(lane&15), k = kt*32 + ((lane>>4)&3)*8 + j. Zero-pad k >= 700.
// ---------------------------------------------------------------------------
__global__ void wprep(const float* __restrict__ Wh, unsigned short* __restrict__ wfrag) {
    int e = blockIdx.x * 256 + threadIdx.x;          // 22*256 = 5632 exact
    int kt   = e >> 8;
    int rem  = e & 255;
    int nf   = rem >> 6;
    int lane = rem & 63;
    int h     = nf * 16 + (lane & 15);
    int kbase = kt * 32 + ((lane >> 4) & 3) * 8;
    unsigned short* dh = wfrag + (size_t)kt * 4096 + (nf * 64 + lane) * 8;
    unsigned short* dl = dh + 2048;
#pragma unroll
    for (int j = 0; j < 8; ++j) {
        int k = kbase + j;
        float v = (k < K_) ? Wh[(size_t)h * K_ + k] : 0.0f;
        unsigned u  = __builtin_bit_cast(unsigned, v);
        float    fh = __builtin_bit_cast(float, u & 0xffff0000u);
        float    r  = v - fh;
        dh[j] = (unsigned short)(u >> 16);
        dl[j] = (unsigned short)(__builtin_bit_cast(unsigned, r) >> 16);
    }
}

// ---------------------------------------------------------------------------
// k1 helpers
// ---------------------------------------------------------------------------
__device__ __forceinline__ void glds16(const void* src, void* lds) {
    __builtin_amdgcn_global_load_lds(
        (const __attribute__((address_space(1))) void*)src,
        (__attribute__((address_space(3))) void*)lds, 16, 0, 0);
}

__device__ __forceinline__ void splitpair(f32x4 p0, f32x4 p1, short8& hi, short8& lo) {
#pragma unroll
    for (int j = 0; j < 4; ++j) {
        {
            unsigned u  = __builtin_bit_cast(unsigned, p0[j]);
            float    fh = __builtin_bit_cast(float, u & 0xffff0000u);
            float    r  = p0[j] - fh;
            hi[j] = (short)(u >> 16);
            lo[j] = (short)(__builtin_bit_cast(unsigned, r) >> 16);
        }
        {
            unsigned u  = __builtin_bit_cast(unsigned, p1[j]);
            float    fh = __builtin_bit_cast(float, u & 0xffff0000u);
            float    r  = p1[j] - fh;
            hi[j + 4] = (short)(u >> 16);
            lo[j + 4] = (short)(__builtin_bit_cast(unsigned, r) >> 16);
        }
    }
}

// stage one x-tile: 128 rows x 32 k = 16KB = 1024 chunks; 4 glds/thread.
// LDS phys (row, pc) holds logical chunk pc ^ (row&7) -> source pre-swizzled.
__device__ __forceinline__ void stage_x32(const float* __restrict__ x, size_t row0,
                                          int kt, int tid, float* sbuf) {
#pragma unroll
    for (int j = 0; j < 4; ++j) {
        int c   = j * 256 + tid;                 // 0..1023
        int row = c >> 3;
        int col = c & 7;
        int csw = (col ^ (row & 7)) << 4;        // pre-swizzled source byte col
        int kbyte = kt * 128 + csw;
        if (kbyte + 16 > K_ * 4) kbyte = 0;      // tail clamp; value * W_pad(0) = 0
        const char* src = (const char*)(x + (row0 + row) * (size_t)K_) + kbyte;
        float* dst = sbuf + (size_t)(c & ~63) * 4;   // wave-uniform base + lane*16B
        glds16(src, dst);
    }
}

// ---------------------------------------------------------------------------
// k1: GEMM. Wave = n-frag (wid), 8 m-frags, W in VGPRs.
// ---------------------------------------------------------------------------
__global__ __launch_bounds__(256, 4) void gemm_cur(const float* __restrict__ x,
                                                   const unsigned short* __restrict__ wfrag,
                                                   const float* __restrict__ b_h,
                                                   float* __restrict__ cur) {
    __shared__ float sbx[2][4096];   // 2 x 16KB x-tiles
    int tid  = threadIdx.x;
    int lane = tid & 63;
    int wid  = tid >> 6;             // n-frag 0..3
    size_t row0 = (size_t)blockIdx.x * 128;

    // W preload: this wave's n-fragment, all 22 k-tiles, hi+lo (176 VGPRs)
    short8 wHi[22], wLo[22];
#pragma unroll
    for (int kt = 0; kt < 22; ++kt) {
        const short8* base = (const short8*)(wfrag + (size_t)kt * 4096);
        wHi[kt] = base[wid * 64 + lane];
        wLo[kt] = base[256 + wid * 64 + lane];
    }
    float bh = b_h[wid * 16 + (lane & 15)];

    f32x4 acc[8];
#pragma unroll
    for (int i = 0; i < 8; ++i) acc[i] = (f32x4){0.f, 0.f, 0.f, 0.f};

    // prologue: stage tiles 0,1 (4 glds/thread each)
    stage_x32(x, row0, 0, tid, sbx[0]);
    stage_x32(x, row0, 1, tid, sbx[1]);

    int g2 = ((lane >> 4) & 3) * 2;

#define GSTEP(KT, N)                                                         \
    {                                                                        \
        asm volatile("s_waitcnt vmcnt(" #N ")" ::: "memory");                \
        __builtin_amdgcn_s_barrier();                                        \
        const f32x4* xb = (const f32x4*)sbx[(KT) & 1];                       \
        short8 bhf = wHi[KT], blf = wLo[KT];                                 \
        _Pragma("unroll")                                                    \
        for (int i = 0; i < 8; ++i) {                                        \
            int r  = i * 16 + (lane & 15);                                   \
            int c0 = r * 8 + (g2 ^ (r & 7));                                 \
            int c1 = r * 8 + ((g2 + 1) ^ (r & 7));                           \
            short8 ah, al;                                                   \
            splitpair(xb[c0], xb[c1], ah, al);                               \
            acc[i] = __builtin_amdgcn_mfma_f32_16x16x32_bf16(ah, bhf, acc[i], 0, 0, 0); \
            acc[i] = __builtin_amdgcn_mfma_f32_16x16x32_bf16(al, bhf, acc[i], 0, 0, 0); \
            acc[i] = __builtin_amdgcn_mfma_f32_16x16x32_bf16(ah, blf, acc[i], 0, 0, 0); \
        }                                                                    \
        asm volatile("s_waitcnt lgkmcnt(0)" ::: "memory");                   \
        __builtin_amdgcn_s_barrier();                                        \
        if ((KT) + 2 < NKT) stage_x32(x, row0, (KT) + 2, tid, sbx[(KT) & 1]); \
    }
    GSTEP(0, 4)   GSTEP(1, 4)   GSTEP(2, 4)   GSTEP(3, 4)   GSTEP(4, 4)
    GSTEP(5, 4)   GSTEP(6, 4)   GSTEP(7, 4)   GSTEP(8, 4)   GSTEP(9, 4)
    GSTEP(10, 4)  GSTEP(11, 4)  GSTEP(12, 4)  GSTEP(13, 4)  GSTEP(14, 4)
    GSTEP(15, 4)  GSTEP(16, 4)  GSTEP(17, 4)  GSTEP(18, 4)  GSTEP(19, 4)
    GSTEP(20, 4)  GSTEP(21, 0)
#undef GSTEP

    // epilogue: t-quad layout cur4[(r>>2)*64 + h]; col = wid*16 + (lane&15)
    f32x4* cur4 = (f32x4*)cur;
#pragma unroll
    for (int i = 0; i < 8; ++i) {
        size_t r4 = row0 + i * 16 + ((lane >> 4) & 3) * 4;
        f32x4 q;
#pragma unroll
        for (int j = 0; j < 4; ++j) q[j] = acc[i][j] + bh;
        cur4[(r4 >> 2) * 64 + wid * 16 + (lane & 15)] = q;
    }
}

// ---------------------------------------------------------------------------
// k2: LIF, chunked speculative. One wave per (batch, chunk); lane = neuron.
// t-quad cur layout: lane h loads f32x4 = 4 consecutive t's (coalesced).
// ---------------------------------------------------------------------------
__global__ __launch_bounds__(64) void lif(const float* __restrict__ cur, ull* __restrict__ masks) {
    int b = blockIdx.x & 255;
    int c = blockIdx.x >> 8;
    int h = threadIdx.x;
    int t0 = c * TCL;
    int ts = (c == 0) ? 0 : (t0 - BIL);
    const f32x4* p = (const f32x4*)cur + (((size_t)b * T_ + ts) >> 2) * 64 + h;
    float v = 0.0f;
    int ngb = (t0 - ts) >> 2;          // burn-in groups (0 or 10)
    for (int g = 0; g < ngb; ++g) {
        f32x4 q = p[g * 64];
#pragma unroll
        for (int j = 0; j < 4; ++j) {
            v = (v + q[j]) * 0.5f;
            v = (v >= 1.0f) ? 0.0f : v;
        }
    }
    p += (size_t)ngb * 64;
    ull* mp = masks + (size_t)b * T_ + t0;
#pragma unroll 2
    for (int g = 0; g < TCL / 4; ++g) {
        f32x4 q = p[g * 64];
#pragma unroll
        for (int j = 0; j < 4; ++j) {
            v = (v + q[j]) * 0.5f;
            bool s = (v >= 1.0f);
            ull m = __ballot(s);
            if (h == 0) mp[g * 4 + j] = m;
            v = s ? 0.0f : v;
        }
    }
}

// ---------------------------------------------------------------------------
// k3: fused readout, one block per batch, 512 threads (8 waves).
// ---------------------------------------------------------------------------
__global__ __launch_bounds__(512) void readout(const ull* __restrict__ masks,
                                               const float* __restrict__ Wr,
                                               const float* __restrict__ br,
                                               const float* __restrict__ tau,
                                               float* __restrict__ out) {
    __shared__ __align__(16) float wt[64][20];     // wt[h][o]
    __shared__ ull  smask[T_];
    __shared__ __align__(16) float E[NCH][20];
    __shared__ __align__(16) float Sv[NCH][20];
    __shared__ __align__(16) float pacc[NCH][20];
    __shared__ __align__(16) float sScale[20], sBase[20], sBeta[20];
    __shared__ float Pg[8][20], Sst[8][20], part[8][20];

    int tid = threadIdx.x;
    int b   = blockIdx.x;
    for (int i = tid; i < 1280; i += 512) wt[i & 63][i >> 6] = Wr[(size_t)(i >> 6) * 64 + (i & 63)];
    for (int i = tid; i < T_; i += 512) smask[i] = masks[(size_t)b * T_ + i];
    if (tid < 20) {
        float beta = 1.0f / (1.0f + __expf(-tau[tid]));
        sBeta[tid]  = beta;
        sScale[tid] = 1.0f - beta;
        sBase[tid]  = br[tid];
    }
    __syncthreads();

    // phase 1: scanE — items (c, o4), NCH*5 = 1000
    for (int it = tid; it < NCH * 5; it += 512) {
        int o4 = it % 5;
        int c  = it / 5;
        f32x4 beta4  = *(const f32x4*)&sBeta[o4 * 4];
        f32x4 scale4 = *(const f32x4*)&sScale[o4 * 4];
        f32x4 base4  = *(const f32x4*)&sBase[o4 * 4];
        f32x4 v = {0.f, 0.f, 0.f, 0.f};
        const ull* mp = smask + c * TCH;
#pragma unroll
        for (int j = 0; j < TCH; ++j) {
            ull m = mp[j];
            f32x4 a = {0.f, 0.f, 0.f, 0.f};
            while (m) {
                int h = __builtin_ctzll(m);
                m &= (m - 1);
                a += *(const f32x4*)&wt[h][o4 * 4];
            }
            f32x4 q;
#pragma unroll
            for (int jj = 0; jj < 4; ++jj) q[jj] = scale4[jj] * (base4[jj] + a[jj]);
            v = beta4 * v + q;
        }
        *(f32x4*)&E[c][o4 * 4] = v;
    }
    __syncthreads();

    // phase 2a: per-(o, g) partial combine over 25 chunks
    if (tid < 160) {
        int o = tid >> 3, g = tid & 7;
        float beta = sBeta[o];
        float b2 = beta * beta;
        float bp = b2 * b2 * beta;               // beta^5
        float P = 0.0f;
        for (int c = g * 25; c < g * 25 + 25; ++c) P = bp * P + E[c][o];
        Pg[g][o] = P;
    }
    __syncthreads();

    // phase 2b: serial combine of 8 groups per o
    if (tid < 20) {
        int o = tid;
        float beta = sBeta[o];
        float b2 = beta * beta;
        float bp = b2 * b2 * beta;
        float bp25 = 1.0f;
#pragma unroll
        for (int i = 0; i < 25; ++i) bp25 *= bp;
        float s = 0.0f;
        for (int g = 0; g < 8; ++g) { Sst[g][o] = s; s = bp25 * s + Pg[g][o]; }
    }
    __syncthreads();

    // phase 2c: re-scan groups to per-chunk starts Sv
    if (tid < 160) {
        int o = tid >> 3, g = tid & 7;
        float beta = sBeta[o];
        float b2 = beta * beta;
        float bp = b2 * b2 * beta;
        float s = Sst[g][o];
        for (int c = g * 25; c < g * 25 + 25; ++c) { Sv[c][o] = s; s = bp * s + E[c][o]; }
    }
    __syncthreads();

    // phase 3: scanSoft — thread c < NCH
    if (tid < NCH) {
        int c = tid;
        float beta[20], v[20], acc[20];
#pragma unroll
        for (int o = 0; o < 20; ++o) {
            beta[o] = sBeta[o];
            v[o]   = Sv[c][o];
            acc[o] = 0.0f;
        }
        int t0 = c * TCH;
        const ull* mp = smask + t0;
#pragma unroll
        for (int j = 0; j < TCH; ++j) {
            int t = t0 + j;
            ull m = mp[j];
            f32x4 a[5];
#pragma unroll
            for (int i = 0; i < 5; ++i) a[i] = (f32x4){0.f, 0.f, 0.f, 0.f};
            while (m) {
                int h = __builtin_ctzll(m);
                m &= (m - 1);
                const f32x4* w4 = (const f32x4*)&wt[h][0];
#pragma unroll
                for (int i = 0; i < 5; ++i) a[i] += w4[i];
            }
#pragma unroll
            for (int o = 0; o < 20; ++o) {
                float q = sScale[o] * (sBase[o] + a[o >> 2][o & 3]);
                v[o] = beta[o] * v[o] + q;
            }
            if (t >= 11) {
                float mx = v[0];
#pragma unroll
                for (int o = 1; o < 20; ++o) mx = fmaxf(mx, v[o]);
                float e[20], ssum = 0.0f;
#pragma unroll
                for (int o = 0; o < 20; ++o) { e[o] = __expf(v[o] - mx); ssum += e[o]; }
                float inv = 1.0f / ssum;
#pragma unroll
                for (int o = 0; o < 20; ++o) acc[o] += e[o] * inv;
            }
        }
#pragma unroll
        for (int o = 0; o < 20; ++o) pacc[c][o] = acc[o];
    }
    __syncthreads();

    // phase 4: reduce — partials then serial-8
    if (tid < 160) {
        int o = tid >> 3, g = tid & 7;
        float s = 0.0f;
        for (int c = g * 25; c < g * 25 + 25; ++c) s += pacc[c][o];
        part[g][o] = s;
    }
    __syncthreads();
    if (tid < 20) {
        float s = 0.0f;
#pragma unroll
        for (int g = 0; g < 8; ++g) s += part[g][tid];
        out[(size_t)b * 20 + tid] = s;
    }
}

// ---------------------------------------------------------------------------
extern "C" void kernel_launch(void* const* d_in, const int* in_sizes, int n_in,
                              void* d_out, int out_size, void* d_ws, size_t ws_size,
                              hipStream_t stream) {
    const float* x   = (const float*)d_in[0];
    const float* W_h = (const float*)d_in[1];
    const float* b_h = (const float*)d_in[2];
    const float* W_r = (const float*)d_in[3];
    const float* b_r = (const float*)d_in[4];
    const float* tau = (const float*)d_in[5];

    char* ws = (char*)d_ws;
    unsigned short* wfrag = (unsigned short*)(ws + OFF_WFRAG);
    float* cur  = (float*)(ws + OFF_CUR);
    ull*   msk  = (ull*)(ws + OFF_MASK);
    float* out  = (float*)d_out;

    wprep<<<22, 256, 0, stream>>>(W_h, wfrag);
    gemm_cur<<<2000, 256, 0, stream>>>(x, wfrag, b_h, cur);
    lif<<<NCL * 256, 64, 0, stream>>>(cur, msk);
    readout<<<256, 512, 0, stream>>>(msk, W_r, b_r, tau, out);
}